// Round 2
// baseline (222.980 us; speedup 1.0000x reference)
//
#include <hip/hip_runtime.h>

// Fused 4-level Haar DWT. Haar 2x2 blocks don't overlap, so a 64x64 input
// tile is self-contained for all 4 levels: level1 32x32 (global+LDS),
// level2 16x16, level3 8x8, level4 4x4 — cascaded through LDS.
// One block per (batch, channel, tile). Reference quirk: b4 = g4, so the
// c==1 (green) tile also writes level-4 into the blue slot; c==2 skips L4.
__global__ __launch_bounds__(256) void dwt_fused_kernel(
    const float* __restrict__ x, float* __restrict__ out)
{
    __shared__ float lds1[32 * 36];   // level-1 LL tile, stride 36 (f4-aligned pad)
    __shared__ float lds2[16 * 18];   // level-2 LL
    __shared__ float lds3[8 * 9];     // level-3 LL

    const int t = threadIdx.x;
    const int tile = blockIdx.x;          // 0..63
    const int tx = tile & 7, ty = tile >> 3;
    const int plane = blockIdx.y;         // 0..95
    const int b = plane / 3, c = plane - 3 * b;

    const long pbase = (long)(b * 12 + c * 4);
    const long off2 = 25165824L;          // 32*12*256*256
    const long off3 = 31457280L;          // + 32*12*128*128
    const long off4 = 33030144L;          // + 32*12*64*64

    // ---------- level 1: global 64x64 -> 4x 32x32 ----------
    {
        const int oi = t >> 3;            // 0..31 output row within tile
        const int oj = t & 7;             // 0..7, each handles 4 output cols
        const float* sp = x + (long)(b * 3 + c) * (512 * 512);
        const int gr = ty * 64 + 2 * oi;
        const int gc = tx * 64 + 8 * oj;
        const float4 r0a = *(const float4*)(sp + (long)gr * 512 + gc);
        const float4 r0b = *(const float4*)(sp + (long)gr * 512 + gc + 4);
        const float4 r1a = *(const float4*)(sp + (long)(gr + 1) * 512 + gc);
        const float4 r1b = *(const float4*)(sp + (long)(gr + 1) * 512 + gc + 4);

        float L0 = (r0a.x + r1a.x) * 0.5f, L1 = (r0a.y + r1a.y) * 0.5f;
        float H0 = fabsf(r0a.x - r1a.x),   H1 = fabsf(r0a.y - r1a.y);
        float L2 = (r0a.z + r1a.z) * 0.5f, L3 = (r0a.w + r1a.w) * 0.5f;
        float H2 = fabsf(r0a.z - r1a.z),   H3 = fabsf(r0a.w - r1a.w);
        float L4 = (r0b.x + r1b.x) * 0.5f, L5 = (r0b.y + r1b.y) * 0.5f;
        float H4 = fabsf(r0b.x - r1b.x),   H5 = fabsf(r0b.y - r1b.y);
        float L6 = (r0b.z + r1b.z) * 0.5f, L7 = (r0b.w + r1b.w) * 0.5f;
        float H6 = fabsf(r0b.z - r1b.z),   H7 = fabsf(r0b.w - r1b.w);

        float4 ll = make_float4((L0 + L1) * 0.5f, (L2 + L3) * 0.5f,
                                (L4 + L5) * 0.5f, (L6 + L7) * 0.5f);
        float4 lh = make_float4(fabsf(L0 - L1), fabsf(L2 - L3),
                                fabsf(L4 - L5), fabsf(L6 - L7));
        float4 hl = make_float4((H0 + H1) * 0.5f, (H2 + H3) * 0.5f,
                                (H4 + H5) * 0.5f, (H6 + H7) * 0.5f);
        float4 hh = make_float4(fabsf(H0 - H1), fabsf(H2 - H3),
                                fabsf(H4 - H5), fabsf(H6 - H7));

        float* dp = out + (long)(ty * 32 + oi) * 256 + (tx * 32 + 4 * oj);
        *(float4*)(dp + (pbase + 0) * 65536) = ll;
        *(float4*)(dp + (pbase + 1) * 65536) = lh;
        *(float4*)(dp + (pbase + 2) * 65536) = hl;
        *(float4*)(dp + (pbase + 3) * 65536) = hh;

        *(float4*)(lds1 + oi * 36 + 4 * oj) = ll;
    }
    __syncthreads();

    // ---------- level 2: LDS 32x32 -> 4x 16x16 ----------
    {
        const int i2 = t >> 4, j2 = t & 15;
        float a  = lds1[(2 * i2) * 36 + 2 * j2];
        float bb = lds1[(2 * i2) * 36 + 2 * j2 + 1];
        float cc = lds1[(2 * i2 + 1) * 36 + 2 * j2];
        float dd = lds1[(2 * i2 + 1) * 36 + 2 * j2 + 1];
        float L0 = (a + cc) * 0.5f, L1 = (bb + dd) * 0.5f;
        float Ha = fabsf(a - cc),   Hb = fabsf(bb - dd);
        float ll = (L0 + L1) * 0.5f, lh = fabsf(L0 - L1);
        float hl = (Ha + Hb) * 0.5f, hh = fabsf(Ha - Hb);

        float* dp = out + off2 + (long)(ty * 16 + i2) * 128 + (tx * 16 + j2);
        dp[(pbase + 0) * 16384] = ll;
        dp[(pbase + 1) * 16384] = lh;
        dp[(pbase + 2) * 16384] = hl;
        dp[(pbase + 3) * 16384] = hh;
        lds2[i2 * 18 + j2] = ll;
    }
    __syncthreads();

    // ---------- level 3: LDS 16x16 -> 4x 8x8 ----------
    if (t < 64) {
        const int i3 = t >> 3, j3 = t & 7;
        float a  = lds2[(2 * i3) * 18 + 2 * j3];
        float bb = lds2[(2 * i3) * 18 + 2 * j3 + 1];
        float cc = lds2[(2 * i3 + 1) * 18 + 2 * j3];
        float dd = lds2[(2 * i3 + 1) * 18 + 2 * j3 + 1];
        float L0 = (a + cc) * 0.5f, L1 = (bb + dd) * 0.5f;
        float Ha = fabsf(a - cc),   Hb = fabsf(bb - dd);
        float ll = (L0 + L1) * 0.5f, lh = fabsf(L0 - L1);
        float hl = (Ha + Hb) * 0.5f, hh = fabsf(Ha - Hb);

        float* dp = out + off3 + (long)(ty * 8 + i3) * 64 + (tx * 8 + j3);
        dp[(pbase + 0) * 4096] = ll;
        dp[(pbase + 1) * 4096] = lh;
        dp[(pbase + 2) * 4096] = hl;
        dp[(pbase + 3) * 4096] = hh;
        lds3[i3 * 9 + j3] = ll;
    }
    __syncthreads();

    // ---------- level 4: LDS 8x8 -> 4x 4x4 (r,g only; b slot = copy of g) ----------
    if (t < 16 && c < 2) {
        const int i4 = t >> 2, j4 = t & 3;
        float a  = lds3[(2 * i4) * 9 + 2 * j4];
        float bb = lds3[(2 * i4) * 9 + 2 * j4 + 1];
        float cc = lds3[(2 * i4 + 1) * 9 + 2 * j4];
        float dd = lds3[(2 * i4 + 1) * 9 + 2 * j4 + 1];
        float L0 = (a + cc) * 0.5f, L1 = (bb + dd) * 0.5f;
        float Ha = fabsf(a - cc),   Hb = fabsf(bb - dd);
        float ll = (L0 + L1) * 0.5f, lh = fabsf(L0 - L1);
        float hl = (Ha + Hb) * 0.5f, hh = fabsf(Ha - Hb);

        float* dp = out + off4 + (long)(ty * 4 + i4) * 32 + (tx * 4 + j4);
        dp[(pbase + 0) * 1024] = ll;
        dp[(pbase + 1) * 1024] = lh;
        dp[(pbase + 2) * 1024] = hl;
        dp[(pbase + 3) * 1024] = hh;
        if (c == 1) {  // reference: b4 = g4
            float* dq = dp + 4 * 1024;
            dq[(pbase + 0) * 1024] = ll;
            dq[(pbase + 1) * 1024] = lh;
            dq[(pbase + 2) * 1024] = hl;
            dq[(pbase + 3) * 1024] = hh;
        }
    }
}

extern "C" void kernel_launch(void* const* d_in, const int* in_sizes, int n_in,
                              void* d_out, int out_size, void* d_ws, size_t ws_size,
                              hipStream_t stream) {
    const float* x = (const float*)d_in[0];
    float* out = (float*)d_out;
    // 64 tiles per 512x512 plane, 96 (batch,channel) planes
    dwt_fused_kernel<<<dim3(64, 96), dim3(256), 0, stream>>>(x, out);
}